// Round 4
// baseline (111.334 us; speedup 1.0000x reference)
//
#include <hip/hip_runtime.h>

// FlowLenia step, SX=SY=256, C=3, K=15. All intermediates PLANAR (xy-innermost)
// to kill address divergence; inputs de-interleaved once in K0.
//   K0 de-interleave A,P -> Aplan[3][XY], Asum[XY], Pplan[15][XY]
//   K1 row-FFT of Aplan (3 planes)                  -> RF [c][x][y] complex
//   K2 fwd col-FFT + fK mul + inv col-FFT per k     -> T2 [k][x][y] complex
//   K3 inv row-FFT + growth*Pplan + collapse        -> Ucol [c][XY]
//   K4 Sobel flow (planar in/out)                   -> Fplan [d*3+c][XY]
//   K5 5x5 reintegration + softmax mix              -> d_out (newA | newP interleaved)

#define XY  65536
#define NC  3
#define NK  15
#define WPAD 260   // per-wave LDS buffer stride (float2), pad to spread banks

__device__ __forceinline__ float2 cmul(float2 a, float2 b) {
  return make_float2(a.x * b.x - a.y * b.y, a.x * b.y + a.y * b.x);
}

// 256-pt Stockham radix-4 FFT on a wave-private 256-float2 LDS buffer pair.
// t = lane (0..63). sign = -1 fwd, +1 inv (unnormalized). Result lands in b0.
// All waves in the block must call this together (identical control flow).
__device__ __forceinline__ void fft256_lds(float2* b0, float2* b1, int t, float sign) {
  float2* src = b0;
  float2* dst = b1;
#pragma unroll
  for (int stage = 0; stage < 4; ++stage) {
    __syncthreads();  // covers caller's fill and previous stage's writes
    const int Ns = 1 << (2 * stage);
    float2 v0 = src[t];
    float2 v1 = src[t + 64];
    float2 v2 = src[t + 128];
    float2 v3 = src[t + 192];
    const int jm = t & (Ns - 1);
    float ang = sign * 6.283185307179586f * (float)jm / (float)(Ns * 4);
    float sn, cs;
    __sincosf(ang, &sn, &cs);
    float2 w1 = make_float2(cs, sn);
    float2 w2 = cmul(w1, w1);
    float2 w3 = cmul(w2, w1);
    v1 = cmul(v1, w1);
    v2 = cmul(v2, w2);
    v3 = cmul(v3, w3);
    float2 a0 = make_float2(v0.x + v2.x, v0.y + v2.y);
    float2 a1 = make_float2(v0.x - v2.x, v0.y - v2.y);
    float2 a2 = make_float2(v1.x + v3.x, v1.y + v3.y);
    float2 a3 = make_float2(v1.x - v3.x, v1.y - v3.y);
    float2 ia3 = make_float2(-sign * a3.y, sign * a3.x);  // (sign*i)*a3
    const int idxD = ((t >> (2 * stage)) << (2 * stage)) * 4 + jm;  // (t/Ns)*4Ns + jm
    dst[idxD]          = make_float2(a0.x + a2.x, a0.y + a2.y);
    dst[idxD + Ns]     = make_float2(a1.x + ia3.x, a1.y + ia3.y);
    dst[idxD + 2 * Ns] = make_float2(a0.x - a2.x, a0.y - a2.y);
    dst[idxD + 3 * Ns] = make_float2(a1.x - ia3.x, a1.y - ia3.y);
    float2* tmp = src; src = dst; dst = tmp;
  }
  __syncthreads();
}

// K0: de-interleave. Per-thread reads are contiguous (12B / 60B per lane ->
// wave covers a contiguous span); planar writes fully coalesced.
// grid = 256 blocks x 256.
__global__ __launch_bounds__(256) void k_prep(const float* __restrict__ A,
                                              const float* __restrict__ P,
                                              float* __restrict__ Aplan,
                                              float* __restrict__ Asum,
                                              float* __restrict__ Pplan) {
  const int b = blockIdx.x * 256 + threadIdx.x;
  float a0 = A[b * 3 + 0], a1 = A[b * 3 + 1], a2 = A[b * 3 + 2];
  Aplan[0 * XY + b] = a0;
  Aplan[1 * XY + b] = a1;
  Aplan[2 * XY + b] = a2;
  Asum[b] = a0 + a1 + a2;
#pragma unroll
  for (int k = 0; k < NK; ++k) Pplan[k * XY + b] = P[b * NK + k];
}

// K1: forward FFT along y, 4 rows per block (4 waves).
// grid = 3*64 blocks x 256.
__global__ __launch_bounds__(256) void k_rowfft(const float* __restrict__ Aplan,
                                                float2* __restrict__ RF) {
  __shared__ float2 lds0[4 * WPAD], lds1[4 * WPAD];
  const int tid = threadIdx.x;
  const int w = tid >> 6, lane = tid & 63;
  const int c = blockIdx.x >> 6;
  const int x = ((blockIdx.x & 63) << 2) + w;
  float2* b0 = lds0 + w * WPAD;
  float2* b1 = lds1 + w * WPAD;
  const float* src = Aplan + c * XY + x * 256;
#pragma unroll
  for (int r = 0; r < 4; ++r) {
    int y = lane + 64 * r;
    b0[y] = make_float2(src[y], 0.0f);
  }
  fft256_lds(b0, b1, lane, -1.0f);
#pragma unroll
  for (int r = 0; r < 4; ++r) {
    int y = lane + 64 * r;
    RF[(c * 256 + x) * 256 + y] = b0[y];
  }
}

// K2: per (k, 8-column tile): fwd col FFT (redundant across the 5 k's of a
// channel -- compute is free), fK multiply, inverse col FFT.
// grid = 15*32 blocks x 512 (8 waves; wave w owns column y0+w).
__global__ __launch_bounds__(512, 1) void k_colfft(const float* __restrict__ fKr,
                                                   const float* __restrict__ fKi,
                                                   const float2* __restrict__ RF,
                                                   float2* __restrict__ T2) {
  __shared__ float2 lds0[8 * WPAD];
  __shared__ float2 lds1[8 * WPAD];
  const int tid = threadIdx.x;
  const int k = blockIdx.x >> 5;
  const int y0 = (blockIdx.x & 31) << 3;
  const int c = k % 3;

  // Tile load: chunk q (16B) of row x holds columns y0+2q, y0+2q+1.
  {
    const int q = tid & 3;
#pragma unroll
    for (int r = 0; r < 2; ++r) {
      const int x = (tid >> 2) + (r << 7);
      const float4* src = (const float4*)(RF + (c * XY + x * 256 + y0));
      float4 v = src[q];
      lds0[(2 * q) * WPAD + x]     = make_float2(v.x, v.y);
      lds0[(2 * q + 1) * WPAD + x] = make_float2(v.z, v.w);
    }
  }

  const int w = tid >> 6, lane = tid & 63;
  float2* b0 = lds0 + w * WPAD;
  float2* b1 = lds1 + w * WPAD;
  fft256_lds(b0, b1, lane, -1.0f);  // leading barrier covers tile fill

  const int y = y0 + w;
  float2 fa[4];
#pragma unroll
  for (int r = 0; r < 4; ++r) fa[r] = b0[lane + 64 * r];
#pragma unroll
  for (int r = 0; r < 4; ++r) {
    const int x = lane + 64 * r;
    const int fi = (x * 256 + y) * NK + k;
    float2 Kv = make_float2(fKr[fi], fKi[fi]);
    b0[x] = cmul(Kv, fa[r]);
  }
  fft256_lds(b0, b1, lane, 1.0f);  // trailing barrier makes lds0 block-visible

  // Tile store: mirror of the load.
  {
    const int q = tid & 3;
#pragma unroll
    for (int r = 0; r < 2; ++r) {
      const int x = (tid >> 2) + (r << 7);
      float2 v0 = lds0[(2 * q) * WPAD + x];
      float2 v1 = lds0[(2 * q + 1) * WPAD + x];
      float4* dst = (float4*)(T2 + (k * XY + x * 256 + y0));
      dst[q] = make_float4(v0.x, v0.y, v1.x, v1.y);
    }
  }
}

// K3: per (c, x): 5 waves, wave j handles k=c+3j: inverse row FFT (contiguous
// T2 reads), growth(U)*Pplan (coalesced), cross-wave collapse -> Ucol channel.
// grid = 3*256 blocks x 320.
__global__ __launch_bounds__(320, 1) void k_irowfft_growth(const float2* __restrict__ T2,
                                                           const float* __restrict__ Pplan,
                                                           const float* __restrict__ m,
                                                           const float* __restrict__ s,
                                                           float* __restrict__ Ucol) {
  __shared__ float2 lds0[5 * WPAD];
  __shared__ float2 lds1[5 * WPAD];
  __shared__ float accs[5 * WPAD];
  const int tid = threadIdx.x;
  const int x = blockIdx.x & 255;
  const int c = blockIdx.x >> 8;
  const int j = tid >> 6, lane = tid & 63;
  const int k = c + 3 * j;

  float2* b0 = lds0 + j * WPAD;
  float2* b1 = lds1 + j * WPAD;
  const float2* src = T2 + (k * XY + x * 256);
#pragma unroll
  for (int r = 0; r < 4; ++r) {
    int y = lane + 64 * r;
    b0[y] = src[y];
  }
  fft256_lds(b0, b1, lane, 1.0f);

  const float mk = m[k];
  const float sk = s[k];
  const float inv2s2 = 0.5f / (sk * sk);
  const float* pk = Pplan + k * XY + x * 256;
#pragma unroll
  for (int r = 0; r < 4; ++r) {
    int y = lane + 64 * r;
    float U = b0[y].x * (1.0f / 65536.0f);
    float d = U - mk;
    float g = 2.0f * __expf(-d * d * inv2s2) - 1.0f;
    accs[j * WPAD + y] = g * pk[y];
  }
  __syncthreads();
  if (tid < 256) {
    float sum = 0.f;
#pragma unroll
    for (int j2 = 0; j2 < 5; ++j2) sum += accs[j2 * WPAD + tid];
    Ucol[c * XY + x * 256 + tid] = sum;
  }
}

// K4: Sobel flow, all planar. Fplan[d*3+c][XY].
// grid = 256 blocks x 256.
__global__ __launch_bounds__(256) void k_flow(const float* __restrict__ Aplan,
                                              const float* __restrict__ Asum,
                                              const float* __restrict__ Ucol,
                                              float* __restrict__ Fplan) {
  const int idx = blockIdx.x * 256 + threadIdx.x;
  const int x = idx >> 8;
  const int y = idx & 255;
  const float MA = 4.35f;

  float u[3][3][3];
  float as[3][3];
#pragma unroll
  for (int di = -1; di <= 1; ++di) {
#pragma unroll
    for (int dj = -1; dj <= 1; ++dj) {
      int xi = x + di, yj = y + dj;
      bool inb = ((unsigned)xi < 256u) && ((unsigned)yj < 256u);
      float a0 = 0.f, a1 = 0.f, a2 = 0.f, asv = 0.f;
      if (inb) {
        int b = xi * 256 + yj;
        a0 = Ucol[0 * XY + b];
        a1 = Ucol[1 * XY + b];
        a2 = Ucol[2 * XY + b];
        asv = Asum[b];
      }
      u[0][di + 1][dj + 1] = a0;
      u[1][di + 1][dj + 1] = a1;
      u[2][di + 1][dj + 1] = a2;
      as[di + 1][dj + 1] = asv;
    }
  }
  float cg0 = (as[2][0] + 2.f * as[2][1] + as[2][2]) -
              (as[0][0] + 2.f * as[0][1] + as[0][2]);
  float cg1 = (as[0][2] + 2.f * as[1][2] + as[2][2]) -
              (as[0][0] + 2.f * as[1][0] + as[2][0]);
  const int b = x * 256 + y;
#pragma unroll
  for (int c = 0; c < NC; ++c) {
    float f0 = (u[c][2][0] + 2.f * u[c][2][1] + u[c][2][2]) -
               (u[c][0][0] + 2.f * u[c][0][1] + u[c][0][2]);
    float f1 = (u[c][0][2] + 2.f * u[c][1][2] + u[c][2][2]) -
               (u[c][0][0] + 2.f * u[c][1][0] + u[c][2][0]);
    float ah = Aplan[c * XY + b] * 0.5f;
    float al = fminf(ah * ah, 1.0f);
    f0 = fminf(fmaxf(f0 * (1.f - al) - cg0 * al, -MA), MA);
    f1 = fminf(fmaxf(f1 * (1.f - al) - cg1 * al, -MA), MA);
    Fplan[(0 * 3 + c) * XY + b] = f0;
    Fplan[(1 * 3 + c) * XY + b] = f1;
  }
}

// K5: reintegration, planar gathers. 5x5 gather is exact: |DT*F| <= 0.87 and
// box halfwidth 0.5+SIGMA = 1.15, so |shift| >= 3 gives area == 0 ->
// exp(0)-1 == 0 contributes nothing. grid = 256 blocks x 256.
__global__ __launch_bounds__(256) void k_reint(const float* __restrict__ Aplan,
                                               const float* __restrict__ Pplan,
                                               const float* __restrict__ Fplan,
                                               float* __restrict__ outA,
                                               float* __restrict__ outP) {
  const int idx = blockIdx.x * 256 + threadIdx.x;
  const int x = idx >> 8;
  const int y = idx & 255;
  const float SIGMA = 0.65f;
  const float INV4S2 = 1.0f / (4.0f * 0.65f * 0.65f);
  const float DT = 0.2f;
  const float px = x + 0.5f;
  const float py = y + 0.5f;

  float accA[3] = {0.f, 0.f, 0.f};
  float accP[15];
#pragma unroll
  for (int k = 0; k < NK; ++k) accP[k] = 0.f;
  float esum = 0.f;

  for (int dx = -2; dx <= 2; ++dx) {
    for (int dy = -2; dy <= 2; ++dy) {
      const int sx = (x - dx) & 255;
      const int sy = (y - dy) & 255;
      const int sb = sx * 256 + sy;
      const float spx = sx + 0.5f;
      const float spy = sy + 0.5f;
      float sumnA = 0.f;
      float nAc[3];
#pragma unroll
      for (int c = 0; c < NC; ++c) {
        float f0 = Fplan[(0 * 3 + c) * XY + sb];
        float f1 = Fplan[(1 * 3 + c) * XY + sb];
        float mu0 = fminf(fmaxf(spx + DT * f0, SIGMA), 256.f - SIGMA);
        float mu1 = fminf(fmaxf(spy + DT * f1, SIGMA), 256.f - SIGMA);
        float sz0 = 0.5f - fabsf(px - mu0) + SIGMA;
        float sz1 = 0.5f - fabsf(py - mu1) + SIGMA;
        sz0 = fminf(fmaxf(sz0, 0.f), 1.f);
        sz1 = fminf(fmaxf(sz1, 0.f), 1.f);
        float area = sz0 * sz1 * INV4S2;
        float na = Aplan[c * XY + sb] * area;
        nAc[c] = na;
        sumnA += na;
      }
      float e = __expf(sumnA) - 1.0f;
      accA[0] += nAc[0];
      accA[1] += nAc[1];
      accA[2] += nAc[2];
      esum += e;
#pragma unroll
      for (int k = 0; k < NK; ++k) accP[k] += Pplan[k * XY + sb] * e;
    }
  }
  const int b = x * 256 + y;
#pragma unroll
  for (int c = 0; c < NC; ++c) outA[b * NC + c] = accA[c];
  const float inv = 1.0f / (esum + 1e-10f);
#pragma unroll
  for (int k = 0; k < NK; ++k) outP[b * NK + k] = accP[k] * inv;
}

extern "C" void kernel_launch(void* const* d_in, const int* in_sizes, int n_in,
                              void* d_out, int out_size, void* d_ws, size_t ws_size,
                              hipStream_t stream) {
  const float* A   = (const float*)d_in[0];
  const float* P   = (const float*)d_in[1];
  const float* fKr = (const float*)d_in[2];
  const float* fKi = (const float*)d_in[3];
  const float* m   = (const float*)d_in[4];
  const float* s   = (const float*)d_in[5];

  float* ws = (float*)d_ws;
  float2* RF    = (float2*)ws;             // 3*XY complex
  float2* T2    = RF + NC * XY;            // 15*XY complex
  float*  Ucol  = (float*)(T2 + NK * XY);  // 3*XY
  float*  Fplan = Ucol + NC * XY;          // 6*XY
  float*  Aplan = Fplan + 6 * XY;          // 3*XY
  float*  Asum  = Aplan + NC * XY;         // XY
  float*  Pplan = Asum + XY;               // 15*XY

  float* outA = (float*)d_out;
  float* outP = outA + NC * XY;

  k_prep<<<256, 256, 0, stream>>>(A, P, Aplan, Asum, Pplan);
  k_rowfft<<<NC * 64, 256, 0, stream>>>(Aplan, RF);
  k_colfft<<<NK * 32, 512, 0, stream>>>(fKr, fKi, RF, T2);
  k_irowfft_growth<<<NC * 256, 320, 0, stream>>>(T2, Pplan, m, s, Ucol);
  k_flow<<<256, 256, 0, stream>>>(Aplan, Asum, Ucol, Fplan);
  k_reint<<<256, 256, 0, stream>>>(Aplan, Pplan, Fplan, outA, outP);
}